// Round 1
// baseline (53.596 us; speedup 1.0000x reference)
//
#include <hip/hip_runtime.h>

// Per-channel histogram: in [LENGTH=1e6, C=64] int32 values in [0,256),
// out [64, 256] int32 counts. Memory-bound: 256 MB read -> ~41 us floor.

#define NCH   64
#define NBINS 256
#define HIST_SIZE (NCH * NBINS)   // 16384 ints = 64 KB LDS
#define THREADS 1024
#define BLOCKS  256               // 1 block/CU, 16 waves/CU

__global__ __launch_bounds__(THREADS) void hist_kernel(
    const int* __restrict__ in, int* __restrict__ out, long long n8)
{
    __shared__ int hist[HIST_SIZE];
    const int tid = threadIdx.x;

    #pragma unroll
    for (int k = 0; k < HIST_SIZE / THREADS; ++k)
        hist[tid + k * THREADS] = 0;
    __syncthreads();

    const int4* __restrict__ in4 = (const int4*)in;
    const long long stride = (long long)gridDim.x * blockDim.x;

    // Each iteration consumes one 8-int (32 B) chunk: chunk i covers flat
    // indices [8i, 8i+8) -> channels (i&7)*8 .. +7 (no wrap since 8 | 64).
    for (long long i = (long long)blockIdx.x * blockDim.x + tid; i < n8; i += stride) {
        int4 a = in4[2 * i];
        int4 b = in4[2 * i + 1];
        const int c0 = (int)((i & 7) << 3);   // base channel of this chunk
        atomicAdd(&hist[(c0 + 0) * NBINS + a.x], 1);
        atomicAdd(&hist[(c0 + 1) * NBINS + a.y], 1);
        atomicAdd(&hist[(c0 + 2) * NBINS + a.z], 1);
        atomicAdd(&hist[(c0 + 3) * NBINS + a.w], 1);
        atomicAdd(&hist[(c0 + 4) * NBINS + b.x], 1);
        atomicAdd(&hist[(c0 + 5) * NBINS + b.y], 1);
        atomicAdd(&hist[(c0 + 6) * NBINS + b.z], 1);
        atomicAdd(&hist[(c0 + 7) * NBINS + b.w], 1);
    }
    __syncthreads();

    // Flush block-private histogram. Integer atomics: exact & order-independent
    // -> deterministic output.
    #pragma unroll
    for (int k = 0; k < HIST_SIZE / THREADS; ++k) {
        const int j = tid + k * THREADS;
        const int v = hist[j];
        if (v) atomicAdd(&out[j], v);
    }
}

extern "C" void kernel_launch(void* const* d_in, const int* in_sizes, int n_in,
                              void* d_out, int out_size, void* d_ws, size_t ws_size,
                              hipStream_t stream) {
    const int* in = (const int*)d_in[0];
    int* out = (int*)d_out;
    const long long n = (long long)in_sizes[0];   // 64,000,000 (divisible by 8)
    const long long n8 = n / 8;

    // Replays accumulate via atomics -> must zero the output every launch.
    hipMemsetAsync(d_out, 0, (size_t)out_size * sizeof(int), stream);

    hist_kernel<<<BLOCKS, THREADS, 0, stream>>>(in, out, n8);
}

// Round 2
// 53.223 us; speedup vs baseline: 1.0070x; 1.0070x over previous
//
#include <hip/hip_runtime.h>

// Per-channel histogram: in [LENGTH=1e6, C=64] int32 values in [0,256),
// out [64, 256] int32 counts. Memory-bound: 256 MB read -> ~41 us floor.
//
// R2 change: flush packs two adjacent bins into one 64-bit atomicAdd
// (2.1M atomics instead of 4.2M) + per-block rotated flush order to spread
// L2 line contention. No carry across the 32-bit halves: per-bin totals
// are ~4e3 << 2^32.

#define NCH   64
#define NBINS 256
#define HIST_SIZE (NCH * NBINS)   // 16384 ints = 64 KB LDS
#define NQWORDS   (HIST_SIZE / 2) // 8192 packed pairs
#define THREADS 1024
#define BLOCKS  256               // 1 block/CU, 16 waves/CU

__global__ __launch_bounds__(THREADS) void hist_kernel(
    const int* __restrict__ in, unsigned long long* __restrict__ out, long long n8)
{
    __shared__ int hist[HIST_SIZE];
    const int tid = threadIdx.x;

    #pragma unroll
    for (int k = 0; k < HIST_SIZE / THREADS; ++k)
        hist[tid + k * THREADS] = 0;
    __syncthreads();

    const int4* __restrict__ in4 = (const int4*)in;
    const long long stride = (long long)gridDim.x * blockDim.x;

    // Each iteration consumes one 8-int (32 B) chunk: chunk i covers flat
    // indices [8i, 8i+8) -> channels (i&7)*8 .. +7 (no wrap since 8 | 64).
    for (long long i = (long long)blockIdx.x * blockDim.x + tid; i < n8; i += stride) {
        int4 a = in4[2 * i];
        int4 b = in4[2 * i + 1];
        const int c0 = (int)((i & 7) << 3);   // base channel of this chunk
        atomicAdd(&hist[(c0 + 0) * NBINS + a.x], 1);
        atomicAdd(&hist[(c0 + 1) * NBINS + a.y], 1);
        atomicAdd(&hist[(c0 + 2) * NBINS + a.z], 1);
        atomicAdd(&hist[(c0 + 3) * NBINS + a.w], 1);
        atomicAdd(&hist[(c0 + 4) * NBINS + b.x], 1);
        atomicAdd(&hist[(c0 + 5) * NBINS + b.y], 1);
        atomicAdd(&hist[(c0 + 6) * NBINS + b.z], 1);
        atomicAdd(&hist[(c0 + 7) * NBINS + b.w], 1);
    }
    __syncthreads();

    // Flush block-private histogram as packed 64-bit adds (two bins/atomic).
    // Rotate start offset per block so blocks spread across L2 lines.
    const unsigned long long* __restrict__ h64 = (const unsigned long long*)hist;
    #pragma unroll
    for (int k = 0; k < NQWORDS / THREADS; ++k) {
        const int j = (tid + k * THREADS + blockIdx.x * 32) & (NQWORDS - 1);
        const unsigned long long v = h64[j];
        if (v) atomicAdd(&out[j], v);
    }
}

extern "C" void kernel_launch(void* const* d_in, const int* in_sizes, int n_in,
                              void* d_out, int out_size, void* d_ws, size_t ws_size,
                              hipStream_t stream) {
    const int* in = (const int*)d_in[0];
    unsigned long long* out = (unsigned long long*)d_out;
    const long long n = (long long)in_sizes[0];   // 64,000,000 (divisible by 8)
    const long long n8 = n / 8;

    // Replays accumulate via atomics -> must zero the output every launch.
    hipMemsetAsync(d_out, 0, (size_t)out_size * sizeof(int), stream);

    hist_kernel<<<BLOCKS, THREADS, 0, stream>>>(in, out, n8);
}